// Round 14
// baseline (358.334 us; speedup 1.0000x reference)
//
#include <hip/hip_runtime.h>
#include <hip/hip_bf16.h>

#define V 49152
#define NNZ 9
#define EPSV 1e-5f
#define SLOPE 0.1f
#define RST 68          // epilogue transpose row stride (floats)

typedef __attribute__((ext_vector_type(8))) short bf16x8;   // 8 bf16 (4 VGPRs)
typedef __attribute__((ext_vector_type(4))) float f32x4;    // MFMA C/D

__device__ __forceinline__ float lo2f(unsigned u) { return __uint_as_float(u << 16); }
__device__ __forceinline__ float hi2f(unsigned u) { return __uint_as_float(u & 0xffff0000u); }
__device__ __forceinline__ unsigned short f2us(float f) {
    __hip_bfloat16 h = __float2bfloat16(f);
    return *(unsigned short*)&h;
}
__device__ __forceinline__ unsigned pk2(float a, float b) {
    return ((unsigned)f2us(a)) | (((unsigned)f2us(b)) << 16);
}
__device__ __forceinline__ void fma8(float* t, float a, uint4 u) {
    t[0] += a * lo2f(u.x); t[1] += a * hi2f(u.x);
    t[2] += a * lo2f(u.y); t[3] += a * hi2f(u.y);
    t[4] += a * lo2f(u.z); t[5] += a * hi2f(u.z);
    t[6] += a * lo2f(u.w); t[7] += a * hi2f(u.w);
}
__device__ __forceinline__ void fold8(float* t, uint4 p) {
    t[0] = 2.f*t[0] - lo2f(p.x); t[1] = 2.f*t[1] - hi2f(p.x);
    t[2] = 2.f*t[2] - lo2f(p.y); t[3] = 2.f*t[3] - hi2f(p.y);
    t[4] = 2.f*t[4] - lo2f(p.z); t[5] = 2.f*t[5] - hi2f(p.z);
    t[6] = 2.f*t[6] - lo2f(p.w); t[7] = 2.f*t[7] - hi2f(p.w);
}
__device__ __forceinline__ uint4 pack8(const float* t) {
    uint4 r;
    r.x = pk2(t[0], t[1]); r.y = pk2(t[2], t[3]);
    r.z = pk2(t[4], t[5]); r.w = pk2(t[6], t[7]);
    return r;
}
__device__ __forceinline__ void gnleaky8(uint4 u, const float* scl, const float* sft, float* y) {
    float e[8] = { lo2f(u.x), hi2f(u.x), lo2f(u.y), hi2f(u.y),
                   lo2f(u.z), hi2f(u.z), lo2f(u.w), hi2f(u.w) };
    #pragma unroll
    for (int i = 0; i < 8; ++i) {
        float t = e[i] * scl[i] + sft[i];
        y[i] = t > 0.f ? t : SLOPE * t;
    }
}
__device__ __forceinline__ void gload_lds16(const void* g, void* l) {
    __builtin_amdgcn_global_load_lds((__attribute__((address_space(1))) void*)g,
                                     (__attribute__((address_space(3))) void*)l, 16, 0, 0);
}

// epilogue pass: transpose one (source, batch) through LDS, emit bf16 + optional GN stats
#define EPI_PASS(SRCM, PB, BI, DSTPTR, DOSTATS)                                     \
    {                                                                               \
        __syncthreads();                                                            \
        _Pragma("unroll")                                                           \
        for (int m_ = 0; m_ < 4; ++m_)                                              \
            _Pragma("unroll")                                                       \
            for (int rr_ = 0; rr_ < 4; ++rr_) {                                     \
                int r_ = m_ * 16 + quad * 4 + rr_;                                  \
                epi[r_ * RST + o] = SRCM[m_][PB][rr_] + (BI);                       \
            }                                                                       \
        __syncthreads();                                                            \
        _Pragma("unroll")                                                           \
        for (int j_ = 0; j_ < 2; ++j_) {                                            \
            int cid_ = (int)threadIdx.x + 256 * j_;                                 \
            int g_ = cid_ & 7, r_ = cid_ >> 3;                                      \
            const float* src_ = epi + r_ * RST + g_ * 8;                            \
            float e_[8], s_ = 0.f, q_ = 0.f;                                        \
            _Pragma("unroll")                                                       \
            for (int i_ = 0; i_ < 8; ++i_) { e_[i_] = src_[i_]; s_ += e_[i_]; q_ += e_[i_] * e_[i_]; } \
            *(uint4*)(void*)((DSTPTR) + ((size_t)(PB) * V + v0 + r_) * 64 + g_ * 8) = pack8(e_); \
            if (DOSTATS) {                                                          \
                atomicAdd(&sGrp[(PB) * 8 + g_], s_);                                \
                atomicAdd(&sGrp[16 + (PB) * 8 + g_], q_);                           \
            }                                                                       \
        }                                                                           \
    }

// ---- prep: weights->bf16 transposed; zero GN partials (64 floats); reorder x -> T0 ----
__global__ __launch_bounds__(256) void prep_reorder_k(
    const float* __restrict__ x, unsigned* __restrict__ t0,
    const float* __restrict__ W1, const float* __restrict__ Wr, const float* __restrict__ W2,
    unsigned short* __restrict__ Wt1, unsigned short* __restrict__ Wtr, unsigned short* __restrict__ Wt2,
    float* __restrict__ part)
{
    int bid = blockIdx.x;
    if (bid < 6144) {                    // reorder: idx < V*32 dwords
        int idx = bid * 256 + threadIdx.x;
        int v = idx >> 5, j2 = idx & 31;
        int b = j2 >> 4, f0 = (j2 & 15) * 2;
        const float* p = x + ((size_t)b * V + v) * 32 + f0;
        t0[idx] = pk2(p[0], p[1]);
    } else {
        int i = (bid - 6144) * 256 + threadIdx.x;
        if (i < 32768) {                 // Wt2[kk][o][f] = W2[kk][f][o], F=64
            int kk = i >> 12, rem = i & 4095, o = rem >> 6, f = rem & 63;
            Wt2[i] = f2us(W2[kk * 4096 + f * 64 + o]);
        } else if (i < 49152) {          // Wt1, F=32
            int j = i - 32768;
            int kk = j >> 11, rem = j & 2047, o = rem >> 5, f = rem & 31;
            Wt1[j] = f2us(W1[kk * 2048 + f * 64 + o]);
        } else if (i < 65536) {          // Wtr, F=32
            int j = i - 49152;
            int kk = j >> 11, rem = j & 2047, o = rem >> 5, f = rem & 31;
            Wtr[j] = f2us(Wr[kk * 2048 + f * 64 + o]);
        } else if (i < 65600) {          // PART1[32] + PART2[32] ONLY
            part[i - 65536] = 0.f;
        }
    }
}

// ============================================================================
// conv1 chain: PANEL-MAJOR hybrid (mirror of the proven conv2 recipe).
// Row = 128B = 2 panels x 64B; panel == batch half (row layout [b*32+f]).
// T0 row-major (from prep); T1..T5 panel [2][V][32sh]; T6 row-major (for
// gemm1f's coalesced T7 gather). panel = blockIdx&1 -> 3.15MB/panel L2-pinned.
// ============================================================================
#define PP1 (V * 32)        // conv1 panel pitch in shorts

template<int SRCROW, int FOLDROW, int ROWOUT, int FIRST>
__global__ __launch_bounds__(256) void spmm1p(
    const unsigned short* __restrict__ zc, const unsigned short* __restrict__ zp,
    unsigned short* __restrict__ zn,
    const float* __restrict__ vals, const int* __restrict__ col)
{
    int p = blockIdx.x & 1;
    int v = (blockIdx.x >> 1) * 64 + (threadIdx.x >> 2);
    int sub = threadIdx.x & 3;
    size_t pb = (size_t)p * PP1;
    float t[8];
    #pragma unroll
    for (int i = 0; i < 8; ++i) t[i] = 0.f;
    int base = v * NNZ;
    #pragma unroll
    for (int n = 0; n < NNZ; ++n) {
        float a = vals[base + n];
        int cc = col[base + n];
        const unsigned short* src = SRCROW
            ? zc + (size_t)cc * 64 + p * 32 + sub * 8
            : zc + pb + (size_t)cc * 32 + sub * 8;
        fma8(t, a, *(const uint4*)(const void*)src);
    }
    if constexpr (!FIRST) {
        const unsigned short* fp = FOLDROW
            ? zp + (size_t)v * 64 + p * 32 + sub * 8
            : zp + pb + (size_t)v * 32 + sub * 8;
        fold8(t, *(const uint4*)(const void*)fp);
    }
    unsigned short* dst = ROWOUT
        ? zn + (size_t)v * 64 + p * 32 + sub * 8
        : zn + pb + (size_t)v * 32 + sub * 8;
    *(uint4*)(void*)dst = pack8(t);
}

// ============================================================================
// conv2 chain: PANEL-MAJOR, XCD-pinned (proven). T slot = [4][V][32sh],
// panel = blockIdx&3; step 6 writes T6 ROW-major (gemm2f T7 gather coalesced).
// ============================================================================
#define PPITCH (V * 32)     // conv2 panel pitch in shorts

template<bool ROWOUT>
__global__ __launch_bounds__(256) void spmm2p(
    const unsigned short* __restrict__ zc, const unsigned short* __restrict__ zp,
    unsigned short* __restrict__ zn,
    const float* __restrict__ vals, const int* __restrict__ col)
{
    int p = blockIdx.x & 3;
    int v = (blockIdx.x >> 2) * 64 + (threadIdx.x >> 2);
    int sub = threadIdx.x & 3;
    size_t pb = (size_t)p * PPITCH;
    float t[8];
    #pragma unroll
    for (int i = 0; i < 8; ++i) t[i] = 0.f;
    int base = v * NNZ;
    #pragma unroll
    for (int n = 0; n < NNZ; ++n) {
        float a = vals[base + n];
        int cc = col[base + n];
        uint4 u = *(const uint4*)(const void*)(zc + pb + (size_t)cc * 32 + sub * 8);
        fma8(t, a, u);
    }
    uint4 pz = *(const uint4*)(const void*)(zp + pb + (size_t)v * 32 + sub * 8);
    fold8(t, pz);
    if constexpr (ROWOUT)
        *(uint4*)(void*)(zn + (size_t)v * 128 + p * 32 + sub * 8) = pack8(t);
    else
        *(uint4*)(void*)(zn + pb + (size_t)v * 32 + sub * 8) = pack8(t);
}

// steps 1 & 2 with GN1 fused. MODE 0: T1 = L@GN(ACC); MODE 1: T2 = 2*(L@T1) - GN(ACC).
template<int MODE>
__global__ __launch_bounds__(256) void spmm2_gn(
    const unsigned short* __restrict__ ACC, const unsigned short* __restrict__ zc,
    unsigned short* __restrict__ zn, const float* __restrict__ part,
    const float* __restrict__ gamma, const float* __restrict__ beta,
    const float* __restrict__ vals, const int* __restrict__ col)
{
    int p = blockIdx.x & 3;
    int v = (blockIdx.x >> 2) * 64 + (threadIdx.x >> 2);
    int sub = threadIdx.x & 3;
    int b = p >> 1;
    int ch0 = (p & 1) * 32 + sub * 8;
    int g = ch0 >> 3, j8 = b * 8 + g;
    const float Nf = (float)V * 8.f;
    float mean = part[j8 * 2] / Nf;
    float rstd = rsqrtf(part[j8 * 2 + 1] / Nf - mean * mean + EPSV);
    float scl[8], sft[8];
    #pragma unroll
    for (int i = 0; i < 8; ++i) {
        scl[i] = rstd * gamma[ch0 + i];
        sft[i] = beta[ch0 + i] - mean * scl[i];
    }
    size_t pb = (size_t)p * PPITCH;

    float t[8];
    #pragma unroll
    for (int i = 0; i < 8; ++i) t[i] = 0.f;
    int base = v * NNZ;
    #pragma unroll
    for (int n = 0; n < NNZ; ++n) {
        float a = vals[base + n];
        int cc = col[base + n];
        if constexpr (MODE == 0) {
            uint4 u = *(const uint4*)(const void*)(ACC + ((size_t)b * V + cc) * 64 + ch0);
            float y[8];
            gnleaky8(u, scl, sft, y);
            #pragma unroll
            for (int i = 0; i < 8; ++i) t[i] += a * y[i];
        } else {
            uint4 u = *(const uint4*)(const void*)(zc + pb + (size_t)cc * 32 + sub * 8);
            fma8(t, a, u);
        }
    }
    if constexpr (MODE == 1) {
        uint4 u = *(const uint4*)(const void*)(ACC + ((size_t)b * V + v) * 64 + ch0);
        float y[8];
        gnleaky8(u, scl, sft, y);
        #pragma unroll
        for (int i = 0; i < 8; ++i) t[i] = 2.f * t[i] - y[i];
    }
    *(uint4*)(void*)(zn + pb + (size_t)v * 32 + sub * 8) = pack8(t);
}

// ---- conv1 GEMM: slot0/6 row-major, slots 1-5 panel-major; panel-blocked LDS
//      [2][64 rows][4 slots] + 2-bit sub-swizzle (panel == batch, sub == quad);
//      T7 in-kernel (T6 row gather, T5 panel fold); schedule unchanged ----
__global__ __launch_bounds__(256) void gemm1f(
    const unsigned short* __restrict__ T,        // conv1 slots, pitch V*64
    const unsigned short* __restrict__ WtA, const unsigned short* __restrict__ WtB,
    const float* __restrict__ biasA, const float* __restrict__ biasB,
    const float* __restrict__ vals, const int* __restrict__ col,
    unsigned short* __restrict__ ACC, unsigned short* __restrict__ RES, float* __restrict__ part)
{
    __shared__ __align__(16) unsigned short shraw[16384];
    __shared__ float sGrp[32];
    float* epi = (float*)shraw;
    unsigned short* bA = shraw;
    unsigned short* bB = shraw + 8192;

    int wv = threadIdx.x >> 6, lane = threadIdx.x & 63;
    int quad = lane >> 4, l15 = lane & 15;
    int v0 = blockIdx.x * 64;
    int ot = wv;

    // slice = 512 chunks: chunk s -> panel s>>8, row (s>>2)&63, slot s&3; sub = slot^(row&3)
    auto stage = [&](int kk, unsigned short* dst, bool rowm) {
        #pragma unroll
        for (int i = 0; i < 2; ++i) {
            int s = (i * 4 + wv) * 64 + lane;
            int row = (s >> 2) & 63, panel = s >> 8, slot = s & 3;
            int sub = slot ^ (row & 3);
            const unsigned short* gp = rowm
                ? T + (size_t)kk * (V * 64) + (size_t)(v0 + row) * 64 + panel * 32 + sub * 8
                : T + (size_t)kk * (V * 64) + (size_t)panel * PP1
                    + (size_t)(v0 + row) * 32 + sub * 8;
            gload_lds16(gp, dst + (size_t)(i * 4 + wv) * 64 * 8);
        }
    };

    f32x4 acc[4][2], accd[4][2];
    auto comp = [&](int kk, const unsigned short* sb) {
        size_t brow = ((size_t)kk * 64 + ot * 16 + l15) * 32 + quad * 8;
        bf16x8 w = *(const bf16x8*)(const void*)(WtA + brow);
        bf16x8 d = *(const bf16x8*)(const void*)(WtB + brow);
        #pragma unroll
        for (int m = 0; m < 4; ++m) {
            int r = m * 16 + l15;
            #pragma unroll
            for (int b = 0; b < 2; ++b) {
                int pos = b * 256 + r * 4 + (quad ^ (r & 3));   // panel == batch
                bf16x8 a = *(const bf16x8*)(const void*)(sb + (size_t)pos * 8);
                acc[m][b]  = __builtin_amdgcn_mfma_f32_16x16x32_bf16(a, w, acc[m][b], 0, 0, 0);
                accd[m][b] = __builtin_amdgcn_mfma_f32_16x16x32_bf16(a, d, accd[m][b], 0, 0, 0);
            }
        }
    };

    stage(0, bA, true); stage(1, bA + 4096, false);
    #pragma unroll
    for (int m = 0; m < 4; ++m)
        #pragma unroll
        for (int b = 0; b < 2; ++b) {
            acc[m][b]  = (f32x4){0.f, 0.f, 0.f, 0.f};
            accd[m][b] = (f32x4){0.f, 0.f, 0.f, 0.f};
        }
    __syncthreads();

    stage(2, bB, false); stage(3, bB + 4096, false);
    comp(0, bA); comp(1, bA + 4096);
    __syncthreads();

    stage(4, bA, false); stage(5, bA + 4096, false);
    comp(2, bB); comp(3, bB + 4096);
    __syncthreads();

    stage(6, bB, true);
    {   // T7 = 2*(L@T6) - T5: T6 row-major gather (256B quads), T5 panel fold
        const unsigned short* T6 = T + (size_t)6 * V * 64;
        const unsigned short* T5 = T + (size_t)5 * V * 64;
        int row = threadIdx.x >> 2, c2 = (threadIdx.x & 3) * 2;
        int gv = v0 + row;
        float t[16];
        #pragma unroll
        for (int i = 0; i < 16; ++i) t[i] = 0.f;
        int base = gv * NNZ;
        #pragma unroll
        for (int n = 0; n < NNZ; ++n) {
            float a = vals[base + n];
            int cc = col[base + n];
            const uint4* p = (const uint4*)(const void*)(T6 + (size_t)cc * 64 + c2 * 8);
            fma8(t, a, p[0]);
            fma8(t + 8, a, p[1]);
        }
        const uint4* pp = (const uint4*)(const void*)
            (T5 + (size_t)(c2 >> 2) * PP1 + (size_t)gv * 32 + (c2 & 3) * 8);
        fold8(t, pp[0]);
        fold8(t + 8, pp[1]);
        uint4* tl = (uint4*)(bB + 4096);
        comp(4, bA); comp(5, bA + 4096);
        #pragma unroll
        for (int q = 0; q < 2; ++q) {
            int c = c2 + q;
            int pos = (c >> 2) * 256 + row * 4 + ((c & 3) ^ (row & 3));
            tl[pos] = pack8(t + q * 8);
        }
    }
    __syncthreads();

    comp(6, bB); comp(7, bB + 4096);

    if (threadIdx.x < 32) sGrp[threadIdx.x] = 0.f;
    int o = ot * 16 + l15;
    float biA = biasA[o], biB = biasB[o];
    EPI_PASS(acc,  0, biA, ACC, true)
    EPI_PASS(acc,  1, biA, ACC, true)
    EPI_PASS(accd, 0, biB, RES, false)
    EPI_PASS(accd, 1, biB, RES, false)
    __syncthreads();
    if (threadIdx.x < 16) {
        atomicAdd(&part[threadIdx.x * 2],     sGrp[threadIdx.x]);
        atomicAdd(&part[threadIdx.x * 2 + 1], sGrp[16 + threadIdx.x]);
    }
}

// ---- conv2 GEMM (unchanged from round-13 best): slots 1-5 panel, slot 6 row,
//      panel-blocked LDS + 2-bit sub-swizzle, T7 in-kernel ----
__global__ __launch_bounds__(256) void gemm2f(
    const unsigned short* __restrict__ T,        // conv2 slots, pitch V*128
    unsigned short* ACC,                         // row-major (read h1 / write h2)
    const float* __restrict__ part1, const float* __restrict__ g1, const float* __restrict__ be1,
    const unsigned short* __restrict__ Wt2, const float* __restrict__ biasA,
    float* __restrict__ part2,
    const float* __restrict__ vals, const int* __restrict__ col)
{
    __shared__ __align__(16) unsigned short shraw[16384];   // 32KB: b0 | b1
    __shared__ float sGrp[32];
    float* epi = (float*)shraw;
    unsigned short* b0 = shraw;
    unsigned short* b1 = shraw + 8192;

    int wv = threadIdx.x >> 6, lane = threadIdx.x & 63;
    int quad = lane >> 4, l15 = lane & 15;
    int v0 = blockIdx.x * 64;
    int ot = wv;
    const float Nf = (float)V * 8.f;

    auto stage = [&](int kk, unsigned short* dst, bool rowm) {
        #pragma unroll
        for (int i = 0; i < 4; ++i) {
            int s = (i * 4 + wv) * 64 + lane;
            int row = (s >> 2) & 63, panel = s >> 8, slot = s & 3;
            int sub = slot ^ (row & 3);
            const unsigned short* gp = rowm
                ? T + (size_t)kk * (V * 128) + (size_t)(v0 + row) * 128 + panel * 32 + sub * 8
                : T + (size_t)kk * (V * 128) + (size_t)panel * PPITCH
                    + (size_t)(v0 + row) * 32 + sub * 8;
            gload_lds16(gp, dst + (size_t)(i * 4 + wv) * 64 * 8);
        }
    };

    f32x4 acc[4][2];
    auto comp = [&](int kk, const unsigned short* sb) {
        size_t brow = ((size_t)kk * 64 + ot * 16 + l15) * 64 + quad * 8;
        bf16x8 w0 = *(const bf16x8*)(const void*)(Wt2 + brow);
        bf16x8 w1 = *(const bf16x8*)(const void*)(Wt2 + brow + 32);
        #pragma unroll
        for (int m = 0; m < 4; ++m) {
            int r = m * 16 + l15;
            #pragma unroll
            for (int b = 0; b < 2; ++b)
                #pragma unroll
                for (int fh = 0; fh < 2; ++fh) {
                    int pos = (b * 2 + fh) * 256 + r * 4 + (quad ^ (r & 3));
                    bf16x8 a = *(const bf16x8*)(const void*)(sb + (size_t)pos * 8);
                    acc[m][b] = __builtin_amdgcn_mfma_f32_16x16x32_bf16(
                        a, fh ? w1 : w0, acc[m][b], 0, 0, 0);
                }
        }
    };

    // prologue: GN-stage slot0 -> b0 (ds_write), DMA T1 -> b1
    stage(1, b1, false);
    {
        int c = threadIdx.x & 15;
        int b = c >> 3, g = c & 7, j8 = b * 8 + g;
        float mean = part1[j8 * 2] / Nf;
        float rstd = rsqrtf(part1[j8 * 2 + 1] / Nf - mean * mean + EPSV);
        int o0 = g * 8;
        float scl[8], sft[8];
        #pragma unroll
        for (int i = 0; i < 8; ++i) {
            scl[i] = rstd * g1[o0 + i];
            sft[i] = be1[o0 + i] - mean * scl[i];
        }
        #pragma unroll
        for (int j = 0; j < 4; ++j) {
            int r = (threadIdx.x >> 4) + 16 * j;
            uint4 aa = *(const uint4*)(const void*)(ACC + ((size_t)b * V + v0 + r) * 64 + o0);
            float y[8];
            gnleaky8(aa, scl, sft, y);
            int pos = (c >> 2) * 256 + r * 4 + ((c & 3) ^ (r & 3));
            *(uint4*)(void*)(b0 + (size_t)pos * 8) = pack8(y);
        }
    }
    #pragma unroll
    for (int m = 0; m < 4; ++m)
        #pragma unroll
        for (int b = 0; b < 2; ++b) acc[m][b] = (f32x4){0.f, 0.f, 0.f, 0.f};
    __syncthreads();

    comp(0, b0);
    __syncthreads();
    stage(2, b0, false); comp(1, b1);
    __syncthreads();
    stage(3, b1, false); comp(2, b0);
    __syncthreads();
    stage(4, b0, false); comp(3, b1);
    __syncthreads();
    stage(5, b1, false); comp(4, b0);
    __syncthreads();
    stage(6, b0, true);  comp(5, b1);
    __syncthreads();
    {   // T7 = 2*(L@T6) - T5; T6 row-major (256B quads), T5 own panel chunk
        const unsigned short* T6 = T + (size_t)6 * V * 128;
        const unsigned short* T5 = T + (size_t)5 * V * 128;
        int row = threadIdx.x >> 2, p = threadIdx.x & 3;
        int gv = v0 + row;
        size_t pb = (size_t)p * PPITCH;
        float t[8 * 4];
        #pragma unroll
        for (int i = 0; i < 32; ++i) t[i] = 0.f;
        int base = gv * NNZ;
        #pragma unroll
        for (int n = 0; n < NNZ; ++n) {
            float a = vals[base + n];
            int cc = col[base + n];
            const uint4* q = (const uint4*)(const void*)(T6 + (size_t)cc * 128 + p * 32);
            fma8(t, a, q[0]);
            fma8(t + 8, a, q[1]);
            fma8(t + 16, a, q[2]);
            fma8(t + 24, a, q[3]);
        }
        const uint4* pz = (const uint4*)(const void*)(T5 + pb + (size_t)gv * 32);
        fold8(t, pz[0]);
        fold8(t + 8, pz[1]);
        fold8(t + 16, pz[2]);
        fold8(t + 24, pz[3]);
        comp(6, b0);
        #pragma unroll
        for (int sub = 0; sub < 4; ++sub) {
            int pos = p * 256 + row * 4 + (sub ^ (row & 3));
            *(uint4*)(void*)(b1 + (size_t)pos * 8) = pack8(t + sub * 8);
        }
    }
    __syncthreads();
    comp(7, b1);

    // epilogue: 2 transpose passes + GN2 partials (ACC row-major)
    if (threadIdx.x < 32) sGrp[threadIdx.x] = 0.f;
    int o = ot * 16 + l15;
    float biA = biasA[o];
    EPI_PASS(acc, 0, biA, ACC, true)
    EPI_PASS(acc, 1, biA, ACC, true)
    __syncthreads();
    if (threadIdx.x < 16) {
        atomicAdd(&part2[threadIdx.x * 2],     sGrp[threadIdx.x]);
        atomicAdd(&part2[threadIdx.x * 2 + 1], sGrp[16 + threadIdx.x]);
    }
}

// ---- final: out = LeakyReLU(GN2(ACC)) + RES (bf16 residual) ----
__global__ __launch_bounds__(256) void final_out(const unsigned short* __restrict__ ACC,
                                                 const unsigned short* __restrict__ RES,
                                                 float* __restrict__ out,
                                                 const float* __restrict__ part,
                                                 const float* __restrict__ gamma, const float* __restrict__ beta) {
    int idx = blockIdx.x * 256 + threadIdx.x;
    int b = idx >= V * 8 ? 1 : 0;
    int r = idx - b * V * 8;
    int v = r >> 3, g = r & 7;
    int j = b * 8 + g;
    const float N = (float)V * 8.f;
    float mean = part[j * 2] / N;
    float rstd = rsqrtf(part[j * 2 + 1] / N - mean * mean + EPSV);
    int o0 = g * 8;
    size_t base = ((size_t)b * V + v) * 64 + o0;
    uint4 aa = *(const uint4*)(const void*)(ACC + base);
    uint4 rr = *(const uint4*)(const void*)(RES + base);
    float e[8] = { lo2f(aa.x), hi2f(aa.x), lo2f(aa.y), hi2f(aa.y),
                   lo2f(aa.z), hi2f(aa.z), lo2f(aa.w), hi2f(aa.w) };
    float re[8] = { lo2f(rr.x), hi2f(rr.x), lo2f(rr.y), hi2f(rr.y),
                    lo2f(rr.z), hi2f(rr.z), lo2f(rr.w), hi2f(rr.w) };
    float y[8];
    #pragma unroll
    for (int i = 0; i < 8; ++i) {
        float t = (e[i] - mean) * rstd * gamma[o0 + i] + beta[o0 + i];
        y[i] = (t > 0.f ? t : SLOPE * t) + re[i];
    }
    float4 w0 = { y[0], y[1], y[2], y[3] };
    float4 w1 = { y[4], y[5], y[6], y[7] };
    *(float4*)(void*)(out + base) = w0;
    *(float4*)(void*)(out + base + 4) = w1;
}

extern "C" void kernel_launch(void* const* d_in, const int* in_sizes, int n_in,
                              void* d_out, int out_size, void* d_ws, size_t ws_size,
                              hipStream_t stream) {
    const float* x    = (const float*)d_in[0];
    const float* vals = (const float*)d_in[1];
    const int*   col  = (const int*)d_in[3];
    const float* W1   = (const float*)d_in[4];
    const float* b1   = (const float*)d_in[5];
    const float* g1   = (const float*)d_in[6];
    const float* be1  = (const float*)d_in[7];
    const float* W2   = (const float*)d_in[8];
    const float* b2   = (const float*)d_in[9];
    const float* g2   = (const float*)d_in[10];
    const float* be2  = (const float*)d_in[11];
    const float* Wr   = (const float*)d_in[12];
    const float* br   = (const float*)d_in[13];
    float* out = (float*)d_out;

    // workspace:
    //   TS 8 slots x V*128 shorts
    //     conv1 (first half of each slot, pitch V*64): T0 row | T1..T5 panel [2][V][32sh] | T6 row
    //     conv2 (pitch V*128): T1..T5 panel [4][V][32sh] | T6 row [V][128sh]
    //   ACC bf16 [2][V][64] | RES bf16 [2][V][64] | Wt1/Wtr/Wt2 | PART1[32] PART2[32]
    unsigned short* TS  = (unsigned short*)d_ws;
    unsigned short* ACC = TS + (size_t)8 * V * 128;
    unsigned short* RES = ACC + (size_t)2 * V * 64;
    unsigned short* Wt1 = RES + (size_t)2 * V * 64;
    unsigned short* Wtr = Wt1 + 8 * 64 * 32;
    unsigned short* Wt2 = Wtr + 8 * 64 * 32;
    float* PART1 = (float*)(Wt2 + 8 * 64 * 64);
    float* PART2 = PART1 + 32;

    prep_reorder_k<<<6404, 256, 0, stream>>>(x, (unsigned*)TS, W1, Wr, W2, Wt1, Wtr, Wt2, PART1);

    // ---- conv1 basis: panel hybrid (T7 inside gemm1f) ----
    unsigned short* T1s[8];
    for (int k = 0; k < 8; ++k) T1s[k] = TS + (size_t)k * V * 64;
    spmm1p<1,0,0,1><<<2 * V / 64, 256, 0, stream>>>(T1s[0], nullptr, T1s[1], vals, col);
    spmm1p<0,1,0,0><<<2 * V / 64, 256, 0, stream>>>(T1s[1], T1s[0], T1s[2], vals, col);
    for (int k = 3; k < 6; ++k)
        spmm1p<0,0,0,0><<<2 * V / 64, 256, 0, stream>>>(T1s[k-1], T1s[k-2], T1s[k], vals, col);
    spmm1p<0,0,1,0><<<2 * V / 64, 256, 0, stream>>>(T1s[5], T1s[4], T1s[6], vals, col);

    gemm1f<<<V / 64, 256, 0, stream>>>(TS, Wt1, Wtr, b1, br, vals, col, ACC, RES, PART1);

    // ---- conv2: panel chain (XCD-pinned), step 6 -> row-major T6; T7 inside gemm2f ----
    unsigned short* T2s[8];
    for (int k = 0; k < 8; ++k) T2s[k] = TS + (size_t)k * V * 128;
    spmm2_gn<0><<<4 * V / 64, 256, 0, stream>>>(ACC, nullptr, T2s[1], PART1, g1, be1, vals, col);
    spmm2_gn<1><<<4 * V / 64, 256, 0, stream>>>(ACC, T2s[1], T2s[2], PART1, g1, be1, vals, col);
    for (int k = 3; k < 6; ++k)
        spmm2p<false><<<4 * V / 64, 256, 0, stream>>>(T2s[k-1], T2s[k-2], T2s[k], vals, col);
    spmm2p<true><<<4 * V / 64, 256, 0, stream>>>(T2s[5], T2s[4], T2s[6], vals, col);

    gemm2f<<<V / 64, 256, 0, stream>>>(TS, ACC, PART1, g1, be1, Wt2, b2, PART2, vals, col);

    final_out<<<2 * V * 8 / 256, 256, 0, stream>>>(ACC, RES, out, PART2, g2, be2);
}

// Round 15
// 351.656 us; speedup vs baseline: 1.0190x; 1.0190x over previous
//
#include <hip/hip_runtime.h>
#include <hip/hip_bf16.h>

#define V 49152
#define NNZ 9
#define EPSV 1e-5f
#define SLOPE 0.1f
#define RST 68          // epilogue transpose row stride (floats)

typedef __attribute__((ext_vector_type(8))) short bf16x8;   // 8 bf16 (4 VGPRs)
typedef __attribute__((ext_vector_type(4))) float f32x4;    // MFMA C/D

__device__ __forceinline__ float lo2f(unsigned u) { return __uint_as_float(u << 16); }
__device__ __forceinline__ float hi2f(unsigned u) { return __uint_as_float(u & 0xffff0000u); }
__device__ __forceinline__ unsigned short f2us(float f) {
    __hip_bfloat16 h = __float2bfloat16(f);
    return *(unsigned short*)&h;
}
__device__ __forceinline__ unsigned pk2(float a, float b) {
    return ((unsigned)f2us(a)) | (((unsigned)f2us(b)) << 16);
}
__device__ __forceinline__ void fma8(float* t, float a, uint4 u) {
    t[0] += a * lo2f(u.x); t[1] += a * hi2f(u.x);
    t[2] += a * lo2f(u.y); t[3] += a * hi2f(u.y);
    t[4] += a * lo2f(u.z); t[5] += a * hi2f(u.z);
    t[6] += a * lo2f(u.w); t[7] += a * hi2f(u.w);
}
__device__ __forceinline__ void fold8(float* t, uint4 p) {
    t[0] = 2.f*t[0] - lo2f(p.x); t[1] = 2.f*t[1] - hi2f(p.x);
    t[2] = 2.f*t[2] - lo2f(p.y); t[3] = 2.f*t[3] - hi2f(p.y);
    t[4] = 2.f*t[4] - lo2f(p.z); t[5] = 2.f*t[5] - hi2f(p.z);
    t[6] = 2.f*t[6] - lo2f(p.w); t[7] = 2.f*t[7] - hi2f(p.w);
}
__device__ __forceinline__ uint4 pack8(const float* t) {
    uint4 r;
    r.x = pk2(t[0], t[1]); r.y = pk2(t[2], t[3]);
    r.z = pk2(t[4], t[5]); r.w = pk2(t[6], t[7]);
    return r;
}
__device__ __forceinline__ void gnleaky8(uint4 u, const float* scl, const float* sft, float* y) {
    float e[8] = { lo2f(u.x), hi2f(u.x), lo2f(u.y), hi2f(u.y),
                   lo2f(u.z), hi2f(u.z), lo2f(u.w), hi2f(u.w) };
    #pragma unroll
    for (int i = 0; i < 8; ++i) {
        float t = e[i] * scl[i] + sft[i];
        y[i] = t > 0.f ? t : SLOPE * t;
    }
}
__device__ __forceinline__ void gload_lds16(const void* g, void* l) {
    __builtin_amdgcn_global_load_lds((__attribute__((address_space(1))) void*)g,
                                     (__attribute__((address_space(3))) void*)l, 16, 0, 0);
}

// epilogue pass: transpose one (source, batch) through LDS, emit bf16 + optional GN stats
#define EPI_PASS(SRCM, PB, BI, DSTPTR, DOSTATS)                                     \
    {                                                                               \
        __syncthreads();                                                            \
        _Pragma("unroll")                                                           \
        for (int m_ = 0; m_ < 4; ++m_)                                              \
            _Pragma("unroll")                                                       \
            for (int rr_ = 0; rr_ < 4; ++rr_) {                                     \
                int r_ = m_ * 16 + quad * 4 + rr_;                                  \
                epi[r_ * RST + o] = SRCM[m_][PB][rr_] + (BI);                       \
            }                                                                       \
        __syncthreads();                                                            \
        _Pragma("unroll")                                                           \
        for (int j_ = 0; j_ < 2; ++j_) {                                            \
            int cid_ = (int)threadIdx.x + 256 * j_;                                 \
            int g_ = cid_ & 7, r_ = cid_ >> 3;                                      \
            const float* src_ = epi + r_ * RST + g_ * 8;                            \
            float e_[8], s_ = 0.f, q_ = 0.f;                                        \
            _Pragma("unroll")                                                       \
            for (int i_ = 0; i_ < 8; ++i_) { e_[i_] = src_[i_]; s_ += e_[i_]; q_ += e_[i_] * e_[i_]; } \
            *(uint4*)(void*)((DSTPTR) + ((size_t)(PB) * V + v0 + r_) * 64 + g_ * 8) = pack8(e_); \
            if (DOSTATS) {                                                          \
                atomicAdd(&sGrp[(PB) * 8 + g_], s_);                                \
                atomicAdd(&sGrp[16 + (PB) * 8 + g_], q_);                           \
            }                                                                       \
        }                                                                           \
    }

// ---- prep: weights->bf16 transposed; zero GN partials (64 floats); reorder x -> T0 ----
__global__ __launch_bounds__(256) void prep_reorder_k(
    const float* __restrict__ x, unsigned* __restrict__ t0,
    const float* __restrict__ W1, const float* __restrict__ Wr, const float* __restrict__ W2,
    unsigned short* __restrict__ Wt1, unsigned short* __restrict__ Wtr, unsigned short* __restrict__ Wt2,
    float* __restrict__ part)
{
    int bid = blockIdx.x;
    if (bid < 6144) {                    // reorder: idx < V*32 dwords
        int idx = bid * 256 + threadIdx.x;
        int v = idx >> 5, j2 = idx & 31;
        int b = j2 >> 4, f0 = (j2 & 15) * 2;
        const float* p = x + ((size_t)b * V + v) * 32 + f0;
        t0[idx] = pk2(p[0], p[1]);
    } else {
        int i = (bid - 6144) * 256 + threadIdx.x;
        if (i < 32768) {                 // Wt2[kk][o][f] = W2[kk][f][o], F=64
            int kk = i >> 12, rem = i & 4095, o = rem >> 6, f = rem & 63;
            Wt2[i] = f2us(W2[kk * 4096 + f * 64 + o]);
        } else if (i < 49152) {          // Wt1, F=32
            int j = i - 32768;
            int kk = j >> 11, rem = j & 2047, o = rem >> 5, f = rem & 31;
            Wt1[j] = f2us(W1[kk * 2048 + f * 64 + o]);
        } else if (i < 65536) {          // Wtr, F=32
            int j = i - 49152;
            int kk = j >> 11, rem = j & 2047, o = rem >> 5, f = rem & 31;
            Wtr[j] = f2us(Wr[kk * 2048 + f * 64 + o]);
        } else if (i < 65600) {          // PART1[32] + PART2[32] ONLY
            part[i - 65536] = 0.f;
        }
    }
}

// ---- conv1 SpMM Chebyshev step (row-major; proven) ----
template<int THR, bool FIRST>
__global__ __launch_bounds__(256) void spmm_step(
    const uint4* __restrict__ zc, const uint4* __restrict__ zp, uint4* __restrict__ zn,
    const float* __restrict__ vals, const int* __restrict__ col)
{
    constexpr int L4 = THR * 2;
    int tid = blockIdx.x * 256 + threadIdx.x;
    int v = tid / THR;
    int c = (tid - v * THR) * 2;
    int base = v * NNZ;
    float t[16];
    #pragma unroll
    for (int i = 0; i < 16; ++i) t[i] = 0.f;
    #pragma unroll
    for (int n = 0; n < NNZ; ++n) {
        float a = vals[base + n];
        int cc = col[base + n];
        const uint4* p = zc + (size_t)cc * L4 + c;
        fma8(t, a, p[0]);
        fma8(t + 8, a, p[1]);
    }
    if (!FIRST) {
        const uint4* pp = zp + (size_t)v * L4 + c;
        fold8(t, pp[0]);
        fold8(t + 8, pp[1]);
    }
    uint4* q = zn + (size_t)v * L4 + c;
    q[0] = pack8(t);
    q[1] = pack8(t + 8);
}

// ============================================================================
// conv2 chain: PANEL-MAJOR, XCD-pinned. T slot = [4 panels][V][32sh(64B)],
// panel = blockIdx&3 -> per-XCD L2 holds its 3.15MB gather working set.
// Step 6 writes T6 ROW-major so gemm2f's T7 gather is 256B-coalesced.
// ============================================================================
#define PPITCH (V * 32)     // panel pitch in shorts

// steps 3..6: zn = 2*(L@zc) - zp. ROWOUT: write row-major [V][128sh].
template<bool ROWOUT>
__global__ __launch_bounds__(256) void spmm2p(
    const unsigned short* __restrict__ zc, const unsigned short* __restrict__ zp,
    unsigned short* __restrict__ zn,
    const float* __restrict__ vals, const int* __restrict__ col)
{
    int p = blockIdx.x & 3;
    int v = (blockIdx.x >> 2) * 64 + (threadIdx.x >> 2);
    int sub = threadIdx.x & 3;
    size_t pb = (size_t)p * PPITCH;
    float t[8];
    #pragma unroll
    for (int i = 0; i < 8; ++i) t[i] = 0.f;
    int base = v * NNZ;
    #pragma unroll
    for (int n = 0; n < NNZ; ++n) {
        float a = vals[base + n];
        int cc = col[base + n];
        uint4 u = *(const uint4*)(const void*)(zc + pb + (size_t)cc * 32 + sub * 8);
        fma8(t, a, u);
    }
    uint4 pz = *(const uint4*)(const void*)(zp + pb + (size_t)v * 32 + sub * 8);
    fold8(t, pz);
    if constexpr (ROWOUT)
        *(uint4*)(void*)(zn + (size_t)v * 128 + p * 32 + sub * 8) = pack8(t);
    else
        *(uint4*)(void*)(zn + pb + (size_t)v * 32 + sub * 8) = pack8(t);
}

// steps 1 & 2 with GN1 fused. MODE 0: T1 = L@GN(ACC); MODE 1: T2 = 2*(L@T1) - GN(ACC).
template<int MODE>
__global__ __launch_bounds__(256) void spmm2_gn(
    const unsigned short* __restrict__ ACC, const unsigned short* __restrict__ zc,
    unsigned short* __restrict__ zn, const float* __restrict__ part,
    const float* __restrict__ gamma, const float* __restrict__ beta,
    const float* __restrict__ vals, const int* __restrict__ col)
{
    int p = blockIdx.x & 3;
    int v = (blockIdx.x >> 2) * 64 + (threadIdx.x >> 2);
    int sub = threadIdx.x & 3;
    int b = p >> 1;
    int ch0 = (p & 1) * 32 + sub * 8;
    int g = ch0 >> 3, j8 = b * 8 + g;
    const float Nf = (float)V * 8.f;
    float mean = part[j8 * 2] / Nf;
    float rstd = rsqrtf(part[j8 * 2 + 1] / Nf - mean * mean + EPSV);
    float scl[8], sft[8];
    #pragma unroll
    for (int i = 0; i < 8; ++i) {
        scl[i] = rstd * gamma[ch0 + i];
        sft[i] = beta[ch0 + i] - mean * scl[i];
    }
    size_t pb = (size_t)p * PPITCH;

    float t[8];
    #pragma unroll
    for (int i = 0; i < 8; ++i) t[i] = 0.f;
    int base = v * NNZ;
    #pragma unroll
    for (int n = 0; n < NNZ; ++n) {
        float a = vals[base + n];
        int cc = col[base + n];
        if constexpr (MODE == 0) {
            uint4 u = *(const uint4*)(const void*)(ACC + ((size_t)b * V + cc) * 64 + ch0);
            float y[8];
            gnleaky8(u, scl, sft, y);
            #pragma unroll
            for (int i = 0; i < 8; ++i) t[i] += a * y[i];
        } else {
            uint4 u = *(const uint4*)(const void*)(zc + pb + (size_t)cc * 32 + sub * 8);
            fma8(t, a, u);
        }
    }
    if constexpr (MODE == 1) {
        uint4 u = *(const uint4*)(const void*)(ACC + ((size_t)b * V + v) * 64 + ch0);
        float y[8];
        gnleaky8(u, scl, sft, y);
        #pragma unroll
        for (int i = 0; i < 8; ++i) t[i] = 2.f * t[i] - y[i];
    }
    *(uint4*)(void*)(zn + pb + (size_t)v * 32 + sub * 8) = pack8(t);
}

// ---- conv1 GEMM (row-major; 2-slice ping-pong, no cap, RES bf16) ----
__global__ __launch_bounds__(256) void gemm1f(
    const unsigned short* __restrict__ T,
    const unsigned short* __restrict__ WtA, const unsigned short* __restrict__ WtB,
    const float* __restrict__ biasA, const float* __restrict__ biasB,
    const float* __restrict__ vals, const int* __restrict__ col,
    unsigned short* __restrict__ ACC, unsigned short* __restrict__ RES, float* __restrict__ part)
{
    __shared__ __align__(16) unsigned short shraw[16384];
    __shared__ float sGrp[32];
    float* epi = (float*)shraw;
    unsigned short* bA = shraw;
    unsigned short* bB = shraw + 8192;

    int wv = threadIdx.x >> 6, lane = threadIdx.x & 63;
    int quad = lane >> 4, l15 = lane & 15;
    int v0 = blockIdx.x * 64;
    int ot = wv;

    auto stage = [&](int kk, unsigned short* dst) {
        #pragma unroll
        for (int i = 0; i < 2; ++i) {
            int s = (i * 4 + wv) * 64 + lane;
            int row = s >> 3, cl = s & 7;
            int cg = cl ^ (row & 7);
            const unsigned short* gp = T + ((size_t)kk * V + v0 + row) * 64 + cg * 8;
            gload_lds16(gp, dst + (size_t)(i * 4 + wv) * 64 * 8);
        }
    };

    f32x4 acc[4][2], accd[4][2];
    auto comp = [&](int kk, const unsigned short* sb) {
        size_t brow = ((size_t)kk * 64 + ot * 16 + l15) * 32 + quad * 8;
        bf16x8 w = *(const bf16x8*)(const void*)(WtA + brow);
        bf16x8 d = *(const bf16x8*)(const void*)(WtB + brow);
        #pragma unroll
        for (int m = 0; m < 4; ++m) {
            int r = m * 16 + l15, rx = r & 7;
            const unsigned short* rbase = sb + (size_t)r * 64;
            #pragma unroll
            for (int b = 0; b < 2; ++b) {
                int s0 = (b * 4 + quad) ^ rx;
                bf16x8 a = *(const bf16x8*)(const void*)(rbase + s0 * 8);
                acc[m][b]  = __builtin_amdgcn_mfma_f32_16x16x32_bf16(a, w, acc[m][b], 0, 0, 0);
                accd[m][b] = __builtin_amdgcn_mfma_f32_16x16x32_bf16(a, d, accd[m][b], 0, 0, 0);
            }
        }
    };

    stage(0, bA); stage(1, bA + 4096);
    #pragma unroll
    for (int m = 0; m < 4; ++m)
        #pragma unroll
        for (int b = 0; b < 2; ++b) {
            acc[m][b]  = (f32x4){0.f, 0.f, 0.f, 0.f};
            accd[m][b] = (f32x4){0.f, 0.f, 0.f, 0.f};
        }
    __syncthreads();

    stage(2, bB); stage(3, bB + 4096);
    comp(0, bA); comp(1, bA + 4096);
    __syncthreads();

    stage(4, bA); stage(5, bA + 4096);
    comp(2, bB); comp(3, bB + 4096);
    __syncthreads();

    stage(6, bB);
    {   // T7 = 2*(L@T6) - T5 (conv1 row-major) -> ds_write bB slice 1
        const unsigned short* T6 = T + (size_t)6 * V * 64;
        const unsigned short* T5 = T + (size_t)5 * V * 64;
        int row = threadIdx.x >> 2, c2 = (threadIdx.x & 3) * 2;
        int gv = v0 + row;
        float t[16];
        #pragma unroll
        for (int i = 0; i < 16; ++i) t[i] = 0.f;
        int base = gv * NNZ;
        #pragma unroll
        for (int n = 0; n < NNZ; ++n) {
            float a = vals[base + n];
            int cc = col[base + n];
            const uint4* p = (const uint4*)(const void*)(T6 + (size_t)cc * 64 + c2 * 8);
            fma8(t, a, p[0]);
            fma8(t + 8, a, p[1]);
        }
        const uint4* pp = (const uint4*)(const void*)(T5 + (size_t)gv * 64 + c2 * 8);
        fold8(t, pp[0]);
        fold8(t + 8, pp[1]);
        uint4* tl = (uint4*)(bB + 4096);
        int r7 = row & 7;
        comp(4, bA); comp(5, bA + 4096);
        tl[row * 8 + (c2 ^ r7)]       = pack8(t);
        tl[row * 8 + ((c2 + 1) ^ r7)] = pack8(t + 8);
    }
    __syncthreads();

    comp(6, bB); comp(7, bB + 4096);

    if (threadIdx.x < 32) sGrp[threadIdx.x] = 0.f;
    int o = ot * 16 + l15;
    float biA = biasA[o], biB = biasB[o];
    EPI_PASS(acc,  0, biA, ACC, true)
    EPI_PASS(acc,  1, biA, ACC, true)
    EPI_PASS(accd, 0, biB, RES, false)
    EPI_PASS(accd, 1, biB, RES, false)
    __syncthreads();
    if (threadIdx.x < 16) {
        atomicAdd(&part[threadIdx.x * 2],     sGrp[threadIdx.x]);
        atomicAdd(&part[threadIdx.x * 2 + 1], sGrp[16 + threadIdx.x]);
    }
}

// ---- conv2 GEMM: slots 1-5 panel-major, slot 6 row-major (T7 gather coalesced),
//      panel-blocked LDS + 2-bit sub-swizzle ----
__global__ __launch_bounds__(256) void gemm2f(
    const unsigned short* __restrict__ T,        // conv2 slots, pitch V*128
    unsigned short* ACC,                         // row-major (read h1 / write h2)
    const float* __restrict__ part1, const float* __restrict__ g1, const float* __restrict__ be1,
    const unsigned short* __restrict__ Wt2, const float* __restrict__ biasA,
    float* __restrict__ part2,
    const float* __restrict__ vals, const int* __restrict__ col)
{
    __shared__ __align__(16) unsigned short shraw[16384];   // 32KB: b0 | b1
    __shared__ float sGrp[32];
    float* epi = (float*)shraw;
    unsigned short* b0 = shraw;
    unsigned short* b1 = shraw + 8192;

    int wv = threadIdx.x >> 6, lane = threadIdx.x & 63;
    int quad = lane >> 4, l15 = lane & 15;
    int v0 = blockIdx.x * 64;
    int ot = wv;
    const float Nf = (float)V * 8.f;

    // slice = 1024 chunks: chunk s -> panel s>>8, row (s>>2)&63, slot s&3; sub = slot^(row&3)
    auto stage = [&](int kk, unsigned short* dst, bool rowm) {
        #pragma unroll
        for (int i = 0; i < 4; ++i) {
            int s = (i * 4 + wv) * 64 + lane;
            int row = (s >> 2) & 63, panel = s >> 8, slot = s & 3;
            int sub = slot ^ (row & 3);
            const unsigned short* gp = rowm
                ? T + (size_t)kk * (V * 128) + (size_t)(v0 + row) * 128 + panel * 32 + sub * 8
                : T + (size_t)kk * (V * 128) + (size_t)panel * PPITCH
                    + (size_t)(v0 + row) * 32 + sub * 8;
            gload_lds16(gp, dst + (size_t)(i * 4 + wv) * 64 * 8);
        }
    };

    f32x4 acc[4][2];
    auto comp = [&](int kk, const unsigned short* sb) {
        size_t brow = ((size_t)kk * 64 + ot * 16 + l15) * 64 + quad * 8;
        bf16x8 w0 = *(const bf16x8*)(const void*)(Wt2 + brow);
        bf16x8 w1 = *(const bf16x8*)(const void*)(Wt2 + brow + 32);
        #pragma unroll
        for (int m = 0; m < 4; ++m) {
            int r = m * 16 + l15;
            #pragma unroll
            for (int b = 0; b < 2; ++b)
                #pragma unroll
                for (int fh = 0; fh < 2; ++fh) {
                    int pos = (b * 2 + fh) * 256 + r * 4 + (quad ^ (r & 3));
                    bf16x8 a = *(const bf16x8*)(const void*)(sb + (size_t)pos * 8);
                    acc[m][b] = __builtin_amdgcn_mfma_f32_16x16x32_bf16(
                        a, fh ? w1 : w0, acc[m][b], 0, 0, 0);
                }
        }
    };

    // prologue: GN-stage slot0 -> b0 (ds_write), DMA T1 -> b1
    stage(1, b1, false);
    {
        int c = threadIdx.x & 15;
        int b = c >> 3, g = c & 7, j8 = b * 8 + g;
        float mean = part1[j8 * 2] / Nf;
        float rstd = rsqrtf(part1[j8 * 2 + 1] / Nf - mean * mean + EPSV);
        int o0 = g * 8;
        float scl[8], sft[8];
        #pragma unroll
        for (int i = 0; i < 8; ++i) {
            scl[i] = rstd * g1[o0 + i];
            sft[i] = be1[o0 + i] - mean * scl[i];
        }
        #pragma unroll
        for (int j = 0; j < 4; ++j) {
            int r = (threadIdx.x >> 4) + 16 * j;
            uint4 aa = *(const uint4*)(const void*)(ACC + ((size_t)b * V + v0 + r) * 64 + o0);
            float y[8];
            gnleaky8(aa, scl, sft, y);
            int pos = (c >> 2) * 256 + r * 4 + ((c & 3) ^ (r & 3));
            *(uint4*)(void*)(b0 + (size_t)pos * 8) = pack8(y);
        }
    }
    #pragma unroll
    for (int m = 0; m < 4; ++m)
        #pragma unroll
        for (int b = 0; b < 2; ++b) acc[m][b] = (f32x4){0.f, 0.f, 0.f, 0.f};
    __syncthreads();

    comp(0, b0);
    __syncthreads();
    stage(2, b0, false); comp(1, b1);
    __syncthreads();
    stage(3, b1, false); comp(2, b0);
    __syncthreads();
    stage(4, b0, false); comp(3, b1);
    __syncthreads();
    stage(5, b1, false); comp(4, b0);
    __syncthreads();
    stage(6, b0, true);  comp(5, b1);
    __syncthreads();
    {   // T7 = 2*(L@T6) - T5; T6 row-major (quad = contiguous 256B gather),
        // T5 fold from own panel chunk; ds_write panel-blocked b1; overlap comp(6,b0)
        const unsigned short* T6 = T + (size_t)6 * V * 128;
        const unsigned short* T5 = T + (size_t)5 * V * 128;
        int row = threadIdx.x >> 2, p = threadIdx.x & 3;
        int gv = v0 + row;
        size_t pb = (size_t)p * PPITCH;
        float t[8 * 4];
        #pragma unroll
        for (int i = 0; i < 32; ++i) t[i] = 0.f;
        int base = gv * NNZ;
        #pragma unroll
        for (int n = 0; n < NNZ; ++n) {
            float a = vals[base + n];
            int cc = col[base + n];
            const uint4* q = (const uint4*)(const void*)(T6 + (size_t)cc * 128 + p * 32);
            fma8(t, a, q[0]);
            fma8(t + 8, a, q[1]);
            fma8(t + 16, a, q[2]);
            fma8(t + 24, a, q[3]);
        }
        const uint4* pz = (const uint4*)(const void*)(T5 + pb + (size_t)gv * 32);
        fold8(t, pz[0]);
        fold8(t + 8, pz[1]);
        fold8(t + 16, pz[2]);
        fold8(t + 24, pz[3]);
        comp(6, b0);
        #pragma unroll
        for (int sub = 0; sub < 4; ++sub) {
            int pos = p * 256 + row * 4 + (sub ^ (row & 3));
            *(uint4*)(void*)(b1 + (size_t)pos * 8) = pack8(t + sub * 8);
        }
    }
    __syncthreads();
    comp(7, b1);

    // epilogue: 2 transpose passes + GN2 partials (ACC row-major)
    if (threadIdx.x < 32) sGrp[threadIdx.x] = 0.f;
    int o = ot * 16 + l15;
    float biA = biasA[o];
    EPI_PASS(acc, 0, biA, ACC, true)
    EPI_PASS(acc, 1, biA, ACC, true)
    __syncthreads();
    if (threadIdx.x < 16) {
        atomicAdd(&part2[threadIdx.x * 2],     sGrp[threadIdx.x]);
        atomicAdd(&part2[threadIdx.x * 2 + 1], sGrp[16 + threadIdx.x]);
    }
}

// ---- final: out = LeakyReLU(GN2(ACC)) + RES (bf16 residual) ----
__global__ __launch_bounds__(256) void final_out(const unsigned short* __restrict__ ACC,
                                                 const unsigned short* __restrict__ RES,
                                                 float* __restrict__ out,
                                                 const float* __restrict__ part,
                                                 const float* __restrict__ gamma, const float* __restrict__ beta) {
    int idx = blockIdx.x * 256 + threadIdx.x;
    int b = idx >= V * 8 ? 1 : 0;
    int r = idx - b * V * 8;
    int v = r >> 3, g = r & 7;
    int j = b * 8 + g;
    const float N = (float)V * 8.f;
    float mean = part[j * 2] / N;
    float rstd = rsqrtf(part[j * 2 + 1] / N - mean * mean + EPSV);
    int o0 = g * 8;
    size_t base = ((size_t)b * V + v) * 64 + o0;
    uint4 aa = *(const uint4*)(const void*)(ACC + base);
    uint4 rr = *(const uint4*)(const void*)(RES + base);
    float e[8] = { lo2f(aa.x), hi2f(aa.x), lo2f(aa.y), hi2f(aa.y),
                   lo2f(aa.z), hi2f(aa.z), lo2f(aa.w), hi2f(aa.w) };
    float re[8] = { lo2f(rr.x), hi2f(rr.x), lo2f(rr.y), hi2f(rr.y),
                    lo2f(rr.z), hi2f(rr.z), lo2f(rr.w), hi2f(rr.w) };
    float y[8];
    #pragma unroll
    for (int i = 0; i < 8; ++i) {
        float t = (e[i] - mean) * rstd * gamma[o0 + i] + beta[o0 + i];
        y[i] = (t > 0.f ? t : SLOPE * t) + re[i];
    }
    float4 w0 = { y[0], y[1], y[2], y[3] };
    float4 w1 = { y[4], y[5], y[6], y[7] };
    *(float4*)(void*)(out + base) = w0;
    *(float4*)(void*)(out + base + 4) = w1;
}

extern "C" void kernel_launch(void* const* d_in, const int* in_sizes, int n_in,
                              void* d_out, int out_size, void* d_ws, size_t ws_size,
                              hipStream_t stream) {
    const float* x    = (const float*)d_in[0];
    const float* vals = (const float*)d_in[1];
    const int*   col  = (const int*)d_in[3];
    const float* W1   = (const float*)d_in[4];
    const float* b1   = (const float*)d_in[5];
    const float* g1   = (const float*)d_in[6];
    const float* be1  = (const float*)d_in[7];
    const float* W2   = (const float*)d_in[8];
    const float* b2   = (const float*)d_in[9];
    const float* g2   = (const float*)d_in[10];
    const float* be2  = (const float*)d_in[11];
    const float* Wr   = (const float*)d_in[12];
    const float* br   = (const float*)d_in[13];
    float* out = (float*)d_out;

    // workspace:
    //   TS 8 slots x V*128 shorts (conv1: row-major [V][64] first half;
    //     conv2: T1..T5 panel-major [4][V][32sh], T6 row-major [V][128sh])
    //   ACC bf16 [2][V][64] | RES bf16 [2][V][64] | Wt1/Wtr/Wt2 | PART1[32] PART2[32]
    unsigned short* TS  = (unsigned short*)d_ws;
    unsigned short* ACC = TS + (size_t)8 * V * 128;
    unsigned short* RES = ACC + (size_t)2 * V * 64;
    unsigned short* Wt1 = RES + (size_t)2 * V * 64;
    unsigned short* Wtr = Wt1 + 8 * 64 * 32;
    unsigned short* Wt2 = Wtr + 8 * 64 * 32;
    float* PART1 = (float*)(Wt2 + 8 * 64 * 64);
    float* PART2 = PART1 + 32;

    prep_reorder_k<<<6404, 256, 0, stream>>>(x, (unsigned*)TS, W1, Wr, W2, Wt1, Wtr, Wt2, PART1);

    // ---- conv1 basis: T1..T6 row-major (T7 inside gemm1f) ----
    uint4* T1s[8];
    for (int k = 0; k < 8; ++k) T1s[k] = (uint4*)(TS + (size_t)k * V * 64);
    spmm_step<4, true><<<V * 4 / 256, 256, 0, stream>>>(T1s[0], nullptr, T1s[1], vals, col);
    for (int k = 2; k < 7; ++k)
        spmm_step<4, false><<<V * 4 / 256, 256, 0, stream>>>(T1s[k-1], T1s[k-2], T1s[k], vals, col);

    gemm1f<<<V / 64, 256, 0, stream>>>(TS, Wt1, Wtr, b1, br, vals, col, ACC, RES, PART1);

    // ---- conv2: panel chain (XCD-pinned), step 6 -> row-major T6; T7 inside gemm2f ----
    unsigned short* T2s[8];
    for (int k = 0; k < 8; ++k) T2s[k] = TS + (size_t)k * V * 128;
    spmm2_gn<0><<<4 * V / 64, 256, 0, stream>>>(ACC, nullptr, T2s[1], PART1, g1, be1, vals, col);
    spmm2_gn<1><<<4 * V / 64, 256, 0, stream>>>(ACC, T2s[1], T2s[2], PART1, g1, be1, vals, col);
    for (int k = 3; k < 6; ++k)
        spmm2p<false><<<4 * V / 64, 256, 0, stream>>>(T2s[k-1], T2s[k-2], T2s[k], vals, col);
    spmm2p<true><<<4 * V / 64, 256, 0, stream>>>(T2s[5], T2s[4], T2s[6], vals, col);

    gemm2f<<<V / 64, 256, 0, stream>>>(TS, ACC, PART1, g1, be1, Wt2, b2, PART2, vals, col);

    final_out<<<2 * V * 8 / 256, 256, 0, stream>>>(ACC, RES, out, PART2, g2, be2);
}